// Round 3
// baseline (531.459 us; speedup 1.0000x reference)
//
#include <hip/hip_runtime.h>
#include <math.h>

#define HID 2048
#define NH 32
#define NKV 8
#define HD 64
#define BB 2
#define SS 2048
#define MTOT (BB * SS) // 4096

typedef __bf16 bf16;
typedef __bf16 bf16x8 __attribute__((ext_vector_type(8)));
typedef __bf16 bf16x4 __attribute__((ext_vector_type(4)));
typedef float f32x4 __attribute__((ext_vector_type(4)));

#define MFMA16(a, b, c) __builtin_amdgcn_mfma_f32_16x16x32_bf16((a), (b), (c), 0, 0, 0)

__device__ __forceinline__ void load_lds16(const void* g, void* l) {
  __builtin_amdgcn_global_load_lds((const __attribute__((address_space(1))) void*)g,
                                   (__attribute__((address_space(3))) void*)l, 16, 0, 0);
}

// ---------------- fp32 -> bf16 convert ----------------
__global__ void cvt_kernel(const float* __restrict__ src, bf16* __restrict__ dst, int n) {
  int i = (blockIdx.x * 256 + threadIdx.x) * 4;
  if (i >= n) return;
  float4 v = *(const float4*)(src + i);
  bf16x4 o;
  o[0] = (bf16)v.x; o[1] = (bf16)v.y; o[2] = (bf16)v.z; o[3] = (bf16)v.w;
  *(bf16x4*)(dst + i) = o;
}

// ---------------- shared 128x128 GEMM core (C = A * W^T, K=2048) ----------------
__device__ __forceinline__ void gemm128_core(const bf16* __restrict__ Ap,
                                             const bf16* __restrict__ Wp,
                                             bf16* As, bf16* Bs, f32x4 acc[4][4]) {
  const int tid = threadIdx.x;
  const int w = tid >> 6, lane = tid & 63;
  const int sr = lane >> 2;          // row within a 16-row staging chunk
  const int scc = (lane & 3) * 8;    // bf16 col offset (16B per lane)
  const int l16 = lane & 15, quad = lane >> 4;
  const int mw = (w >> 1) * 64, nw = (w & 1) * 64;

  const bf16* gA = Ap + (size_t)(w * 32 + sr) * HID + scc;
  const bf16* gB = Wp + (size_t)(w * 32 + sr) * HID + scc;
  bf16* lA = As + (w * 32) * 32;
  bf16* lB = Bs + (w * 32) * 32;

  for (int k0 = 0; k0 < HID; k0 += 32) {
    load_lds16(gA + k0, lA);
    load_lds16(gA + k0 + (size_t)16 * HID, lA + 16 * 32);
    load_lds16(gB + k0, lB);
    load_lds16(gB + k0 + (size_t)16 * HID, lB + 16 * 32);
    __syncthreads();
    bf16x8 af[4], bfr[4];
#pragma unroll
    for (int mi = 0; mi < 4; ++mi)
      af[mi] = *(const bf16x8*)&As[(mw + mi * 16 + l16) * 32 + quad * 8];
#pragma unroll
    for (int ni = 0; ni < 4; ++ni)
      bfr[ni] = *(const bf16x8*)&Bs[(nw + ni * 16 + l16) * 32 + quad * 8];
#pragma unroll
    for (int mi = 0; mi < 4; ++mi)
#pragma unroll
      for (int ni = 0; ni < 4; ++ni)
        acc[mi][ni] = MFMA16(af[mi], bfr[ni], acc[mi][ni]);
    __syncthreads();
  }
}

// ---------------- fused QKV projection ----------------
// Q output is pre-scaled by 1/sqrt(HD) * log2(e) so attn works in log2 domain
// with zero per-iteration scaling cost.
#define QSCALE 0.1803368801f
__global__ __launch_bounds__(256) void gemm_qkv(const bf16* __restrict__ A,
                                                const bf16* __restrict__ Wq,
                                                const bf16* __restrict__ Wk,
                                                const bf16* __restrict__ Wv,
                                                bf16* __restrict__ Qb,
                                                bf16* __restrict__ Kb,
                                                bf16* __restrict__ Vt) {
  __shared__ bf16 As[128 * 32];
  __shared__ bf16 Bs[128 * 32];
  const int tileM = blockIdx.x * 128;
  const int n0 = blockIdx.y * 128;
  const bf16* Wp;
  int mode;
  if (n0 < HID) { Wp = Wq + (size_t)n0 * HID; mode = 0; }
  else if (n0 < HID + 512) { Wp = Wk + (size_t)(n0 - HID) * HID; mode = 1; }
  else { Wp = Wv + (size_t)(n0 - HID - 512) * HID; mode = 2; }

  f32x4 acc[4][4];
#pragma unroll
  for (int i = 0; i < 4; ++i)
#pragma unroll
    for (int j = 0; j < 4; ++j) acc[i][j] = (f32x4){0.f, 0.f, 0.f, 0.f};

  gemm128_core(A + (size_t)tileM * HID, Wp, As, Bs, acc);

  const int tid = threadIdx.x;
  const int w = tid >> 6, lane = tid & 63;
  const int l16 = lane & 15, quad = lane >> 4;
  const int mw = (w >> 1) * 64, nw = (w & 1) * 64;
#pragma unroll
  for (int mi = 0; mi < 4; ++mi) {
#pragma unroll
    for (int ni = 0; ni < 4; ++ni) {
#pragma unroll
      for (int r = 0; r < 4; ++r) {
        int grow = tileM + mw + mi * 16 + quad * 4 + r;
        int gcol = n0 + nw + ni * 16 + l16;
        float v = acc[mi][ni][r];
        int b = grow >> 11, spos = grow & (SS - 1);
        if (mode == 0) {
          Qb[(size_t)grow * HID + gcol] = (bf16)(v * QSCALE);
        } else if (mode == 1) {
          int nk = gcol - HID;
          Kb[(((size_t)(b * NKV + (nk >> 6))) * SS + spos) * HD + (nk & 63)] = (bf16)v;
        } else {
          int nv = gcol - HID - 512;
          Vt[(((size_t)(b * NKV + (nv >> 6))) * HD + (nv & 63)) * SS + spos] = (bf16)v;
        }
      }
    }
  }
}

// ---------------- output projection ----------------
__global__ __launch_bounds__(256) void gemm_out(const bf16* __restrict__ A,
                                                const bf16* __restrict__ Wo,
                                                float* __restrict__ out) {
  __shared__ bf16 As[128 * 32];
  __shared__ bf16 Bs[128 * 32];
  const int tileM = blockIdx.x * 128;
  const int n0 = blockIdx.y * 128;
  f32x4 acc[4][4];
#pragma unroll
  for (int i = 0; i < 4; ++i)
#pragma unroll
    for (int j = 0; j < 4; ++j) acc[i][j] = (f32x4){0.f, 0.f, 0.f, 0.f};

  gemm128_core(A + (size_t)tileM * HID, Wo + (size_t)n0 * HID, As, Bs, acc);

  const int tid = threadIdx.x;
  const int w = tid >> 6, lane = tid & 63;
  const int l16 = lane & 15, quad = lane >> 4;
  const int mw = (w >> 1) * 64, nw = (w & 1) * 64;
#pragma unroll
  for (int mi = 0; mi < 4; ++mi)
#pragma unroll
    for (int ni = 0; ni < 4; ++ni)
#pragma unroll
      for (int r = 0; r < 4; ++r) {
        int grow = tileM + mw + mi * 16 + quad * 4 + r;
        int gcol = n0 + nw + ni * 16 + l16;
        out[(size_t)grow * HID + gcol] = acc[mi][ni][r];
      }
}

// ---------------- RoPE ----------------
__global__ void rope_q(bf16* __restrict__ Qb) {
  int idx = blockIdx.x * 256 + threadIdx.x;   // 2^22 threads
  int i = idx & 31;
  int h = (idx >> 5) & 31;
  int spos = (idx >> 10) & (SS - 1);
  int b = idx >> 21;
  bf16* p = Qb + ((size_t)(b * SS + spos)) * HID + h * HD;
  float x1 = (float)p[i], x2 = (float)p[i + 32];
  float ex = (float)i * (1.0f / 32.0f);
  float inv = 1.0f / powf(10000.0f, ex);
  float fr = (float)spos * inv;
  float sn, cs;
  sincosf(fr, &sn, &cs);
  p[i] = (bf16)(x1 * cs - x2 * sn);
  p[i + 32] = (bf16)(x2 * cs + x1 * sn);
}

__global__ void rope_k(bf16* __restrict__ Kb) {
  int idx = blockIdx.x * 256 + threadIdx.x;   // 2^20 threads
  int i = idx & 31;
  int spos = (idx >> 5) & (SS - 1);
  int kvh = (idx >> 16) & 7;
  int b = idx >> 19;
  bf16* p = Kb + (((size_t)(b * NKV + kvh)) * SS + spos) * HD;
  float x1 = (float)p[i], x2 = (float)p[i + 32];
  float ex = (float)i * (1.0f / 32.0f);
  float inv = 1.0f / powf(10000.0f, ex);
  float fr = (float)spos * inv;
  float sn, cs;
  sincosf(fr, &sn, &cs);
  p[i] = (bf16)(x1 * cs - x2 * sn);
  p[i + 32] = (bf16)(x2 * cs + x1 * sn);
}

// ---------------- flash attention v3 (software-pipelined register loads) ----------------
// grid: (16, BB*NH); block 256 (4 independent waves, no barriers).
// Block x handles q-tiles {x, 31-x}: exactly 33 kt-iterations per wave.
// Pipeline per iteration: [wait kf] QK-MFMA -> issue vf(kt) first, kf(kt+1)
// after QK (register rotate-in-place) -> softmax covers both latencies ->
// [wait vf] PV-MFMA. The kf prefetch on the final iteration reads <=8KB past
// the (b,kvh) K slice; Kb is followed by Vt inside d_ws, so it stays in-bounds.
#define PSTR 72
__global__ __launch_bounds__(256, 4) void attn(const bf16* __restrict__ Qb,
                                               const bf16* __restrict__ Kb,
                                               const bf16* __restrict__ Vt,
                                               bf16* __restrict__ Ctx) {
  __shared__ bf16 Pbuf[4][16 * PSTR];
  const int tid = threadIdx.x;
  const int w = tid >> 6, lane = tid & 63;
  const int l16 = lane & 15, quad = lane >> 4;
  const int bh = blockIdx.y, b = bh >> 5, h = bh & 31, kvh = h >> 2;
  bf16* Pw = &Pbuf[w][0];
  const char* Kbase = (const char*)(Kb + ((size_t)(b * NKV + kvh)) * SS * HD);
  const char* Vbase = (const char*)(Vt + ((size_t)(b * NKV + kvh)) * HD * SS);
  const int qrel = w * 16 + l16;

  for (int t = 0; t < 2; ++t) {
    const int qt = t ? (31 - (int)blockIdx.x) : (int)blockIdx.x;
    const int q = qt * 64 + qrel;

    const bf16* Qp = Qb + ((size_t)(b * SS + q)) * HID + h * HD + quad * 8;
    bf16x8 qb0 = *(const bf16x8*)Qp;
    bf16x8 qb1 = *(const bf16x8*)(Qp + 32);

    float m = -1e30f, l = 0.f;
    f32x4 oacc[4];
#pragma unroll
    for (int d = 0; d < 4; ++d) oacc[d] = (f32x4){0.f, 0.f, 0.f, 0.f};

    // byte offsets (advance per kt)
    int voK[4], voV[4];
#pragma unroll
    for (int nt = 0; nt < 4; ++nt) voK[nt] = ((nt * 16 + l16) * HD + quad * 8) * 2;
#pragma unroll
    for (int dn = 0; dn < 4; ++dn) voV[dn] = ((dn * 16 + l16) * SS + quad * 8) * 2;

    // preload K fragments for kt=0
    bf16x8 kf[8];
#pragma unroll
    for (int nt = 0; nt < 4; ++nt) {
      kf[2 * nt]     = *(const bf16x8*)(Kbase + voK[nt]);
      kf[2 * nt + 1] = *(const bf16x8*)(Kbase + voK[nt] + 64);
    }

    for (int kt = 0; kt <= qt; ++kt) {
      // V fragments for this iteration (consumed after softmax)
      bf16x8 vf[8];
#pragma unroll
      for (int dn = 0; dn < 4; ++dn) {
        vf[2 * dn]     = *(const bf16x8*)(Vbase + voV[dn]);
        vf[2 * dn + 1] = *(const bf16x8*)(Vbase + voV[dn] + 64);
        voV[dn] += 128;
      }
      // QK^T (S^T tile: row = key, col = q); consumes kf
      f32x4 sc[4];
#pragma unroll
      for (int nt = 0; nt < 4; ++nt) {
        f32x4 s = {0.f, 0.f, 0.f, 0.f};
        s = MFMA16(kf[2 * nt], qb0, s);
        s = MFMA16(kf[2 * nt + 1], qb1, s);
        sc[nt] = s;
      }
      // prefetch K fragments for kt+1 (rotate in place; covered by softmax+PV)
#pragma unroll
      for (int nt = 0; nt < 4; ++nt) {
        voK[nt] += 8192;
        kf[2 * nt]     = *(const bf16x8*)(Kbase + voK[nt]);
        kf[2 * nt + 1] = *(const bf16x8*)(Kbase + voK[nt] + 64);
      }
      // causal mask only on the diagonal tile (wave-uniform branch)
      if (kt == qt) {
#pragma unroll
        for (int nt = 0; nt < 4; ++nt) {
          const int krel = nt * 16 + quad * 4;
#pragma unroll
          for (int r = 0; r < 4; ++r)
            if (krel + r > qrel) sc[nt][r] = -1e9f;
        }
      }
      // online softmax in log2 domain (scale pre-folded into Q)
      float mx = fmaxf(fmaxf(sc[0][0], sc[0][1]), fmaxf(sc[0][2], sc[0][3]));
#pragma unroll
      for (int nt = 1; nt < 4; ++nt)
        mx = fmaxf(mx, fmaxf(fmaxf(sc[nt][0], sc[nt][1]), fmaxf(sc[nt][2], sc[nt][3])));
      mx = fmaxf(mx, __shfl_xor(mx, 16));
      mx = fmaxf(mx, __shfl_xor(mx, 32));
      const float mn = fmaxf(m, mx);
      const float alpha = __builtin_amdgcn_exp2f(m - mn);
      m = mn;

      float rs = 0.f;
#pragma unroll
      for (int nt = 0; nt < 4; ++nt) {
        bf16x4 pk;
#pragma unroll
        for (int r = 0; r < 4; ++r) {
          float p = __builtin_amdgcn_exp2f(sc[nt][r] - m);
          rs += p;
          pk[r] = (bf16)p;
        }
        *(bf16x4*)&Pw[l16 * PSTR + nt * 16 + quad * 4] = pk;
      }
      l = l * alpha + rs;   // per-lane partial; cross-quad combine deferred
#pragma unroll
      for (int dn = 0; dn < 4; ++dn) oacc[dn] *= alpha;

      bf16x8 p0 = *(const bf16x8*)&Pw[l16 * PSTR + quad * 8];
      bf16x8 p1 = *(const bf16x8*)&Pw[l16 * PSTR + 32 + quad * 8];
#pragma unroll
      for (int dn = 0; dn < 4; ++dn) {
        oacc[dn] = MFMA16(vf[2 * dn], p0, oacc[dn]);  // O^T: row = d, col = q
        oacc[dn] = MFMA16(vf[2 * dn + 1], p1, oacc[dn]);
      }
    }

    l += __shfl_xor(l, 16);
    l += __shfl_xor(l, 32);
    const float inv = 1.0f / l;
    bf16* Cp = Ctx + ((size_t)(b * SS + q)) * HID + h * HD + quad * 4;
#pragma unroll
    for (int dn = 0; dn < 4; ++dn) {
      bf16x4 ov;
#pragma unroll
      for (int r = 0; r < 4; ++r) ov[r] = (bf16)(oacc[dn][r] * inv);
      *(bf16x4*)(Cp + dn * 16) = ov;
    }
  }
}

// ---------------- launch ----------------
extern "C" void kernel_launch(void* const* d_in, const int* in_sizes, int n_in,
                              void* d_out, int out_size, void* d_ws, size_t ws_size,
                              hipStream_t stream) {
  const float* hs = (const float*)d_in[0];
  // d_in[1] = attention_mask (pure causal, implemented analytically)
  const float* Wq = (const float*)d_in[2];
  const float* Wk = (const float*)d_in[3];
  const float* Wv = (const float*)d_in[4];
  const float* Wo = (const float*)d_in[5];

  char* ws = (char*)d_ws;
  bf16* A_b  = (bf16*)(ws);              // 16 MB ; reused as Ctx after QKV gemm
  bf16* Wq_b = (bf16*)(ws + 16777216);   // 8 MB
  bf16* Wk_b = (bf16*)(ws + 25165824);   // 2 MB
  bf16* Wv_b = (bf16*)(ws + 27262976);   // 2 MB
  bf16* Wo_b = (bf16*)(ws + 29360128);   // 8 MB
  bf16* Qb   = (bf16*)(ws + 37748736);   // 16 MB
  bf16* Kb   = (bf16*)(ws + 54525952);   // 4 MB
  bf16* Vt   = (bf16*)(ws + 58720256);   // 4 MB  (end: 62914560)
  bf16* Ctx  = A_b;                      // alias: A dead after gemm_qkv

  cvt_kernel<<<8192, 256, 0, stream>>>(hs, A_b, MTOT * HID);
  cvt_kernel<<<4096, 256, 0, stream>>>(Wq, Wq_b, HID * HID);
  cvt_kernel<<<1024, 256, 0, stream>>>(Wk, Wk_b, 512 * HID);
  cvt_kernel<<<1024, 256, 0, stream>>>(Wv, Wv_b, 512 * HID);
  cvt_kernel<<<4096, 256, 0, stream>>>(Wo, Wo_b, HID * HID);

  gemm_qkv<<<dim3(MTOT / 128, 24), 256, 0, stream>>>(A_b, Wq_b, Wk_b, Wv_b, Qb, Kb, Vt);
  rope_q<<<16384, 256, 0, stream>>>(Qb);
  rope_k<<<4096, 256, 0, stream>>>(Kb);
  attn<<<dim3(16, BB * NH), 256, 0, stream>>>(Qb, Kb, Vt, Ctx);
  gemm_out<<<dim3(MTOT / 128, HID / 128), 256, 0, stream>>>(Ctx, Wo_b, (float*)d_out);
}